// Round 15
// baseline (368.984 us; speedup 1.0000x reference)
//
#include <hip/hip_runtime.h>
#include <hip/hip_bf16.h>

typedef __bf16 bf16x8 __attribute__((ext_vector_type(8)));
typedef float  f32x4  __attribute__((ext_vector_type(4)));

#define C_DIM   200
#define HW_DIM  1024
#define NT      13            // 13 row/col tiles of 16 (padded 208)
#define PADC    208
#define BK      64            // k-elems staged per iteration
#define KHALF   8             // k-chunks per block (K-split: 2 blocks/batch)
#define ROWB    128           // bytes per LDS tile row (64 bf16)
#define TILEB   (PADC*ROWB)   // 26624 B per buffer
#define SLAB    (PADC*HW_DIM) // bf16 elems per ws slab
#define GSIZE   (PADC*PADC)   // fp32 elems per partial-G
#define PART_OFF ((size_t)112*1024*1024)   // partials start 112 MB into ws

// global_load_lds: LDS dest = wave-uniform base + lane*16 (linear);
// global source is per-lane (pre-swizzled so data lands swizzled).
#define GLD16(gp, lp) __builtin_amdgcn_global_load_lds(                      \
    (const __attribute__((address_space(1))) unsigned int*)(gp),             \
    (__attribute__((address_space(3))) unsigned int*)(lp), 16, 0, 0)

__device__ __forceinline__ bf16x8 pack8(float4 a, float4 b){
  bf16x8 v;
  v[0]=(__bf16)a.x; v[1]=(__bf16)a.y; v[2]=(__bf16)a.z; v[3]=(__bf16)a.w;
  v[4]=(__bf16)b.x; v[5]=(__bf16)b.y; v[6]=(__bf16)b.z; v[7]=(__bf16)b.w;
  return v;
}

// ======================= kernel 1: partial Gram =========================
// grid 512: block (b,h) computes G_h = X[:,h*512:(h+1)*512] gram partial.
// 2 blocks/CU co-resident -> mutual latency hiding (the r14 diagnosis).
__global__ __launch_bounds__(832, 4)
void gram_partial_kernel(const float* __restrict__ x,
                         __hip_bfloat16* __restrict__ ws,
                         float* __restrict__ part)
{
  __shared__ __align__(16) char sA[2][TILEB];

  const int tid = threadIdx.x;
  const int b   = blockIdx.x >> 1;
  const int h   = blockIdx.x & 1;
  const int k0  = h * KHALF;          // first k-chunk of this block
  const int w   = tid >> 6;
  const int l   = tid & 63;
  const int g   = l >> 4;
  const int c   = l & 15;

  const float*    xb = x  + (size_t)b * (C_DIM * HW_DIM);
  __hip_bfloat16* wb = ws + (size_t)b * SLAB;

  // conversion slots: 200 rows x 8 sub-chunks; thread t -> slots t, t+832
  const int r_a = tid >> 3,  c8_a = tid & 7;
  const int s_b = tid + 832;
  const int r_b = s_b >> 3,  c8_b = s_b & 7;
  const bool vb = (s_b < 1600);

  // DMA staging (proven r13/r14): pre-swizzled source, linear LDS dest
  const int si = l >> 3;
  const int sc = (l & 7) ^ si;
  const int i0 = 2*w, i1 = 2*w + 1;
  const __hip_bfloat16* gs0 = wb + (size_t)(8*i0 + si)*HW_DIM + sc*8;
  const __hip_bfloat16* gs1 = wb + (size_t)(8*i1 + si)*HW_DIM + sc*8;

  f32x4 acc[NT];
  #pragma unroll
  for (int j=0;j<NT;++j) acc[j] = (f32x4){0.f,0.f,0.f,0.f};

  // prologue: convert this block's chunks k0, k0+1 into the slab
  #pragma unroll
  for (int cc = 0; cc < 2; ++cc){
    {
      const size_t o = (size_t)r_a*HW_DIM + (k0+cc)*BK + c8_a*8;
      float4 f0 = *(const float4*)(xb + o), f1 = *(const float4*)(xb + o + 4);
      *reinterpret_cast<bf16x8*>(wb + o) = pack8(f0,f1);
    }
    if (vb){
      const size_t o = (size_t)r_b*HW_DIM + (k0+cc)*BK + c8_b*8;
      float4 f0 = *(const float4*)(xb + o), f1 = *(const float4*)(xb + o + 4);
      *reinterpret_cast<bf16x8*>(wb + o) = pack8(f0,f1);
    }
  }
  __syncthreads();                       // slab chunks k0..k0+1 visible

  GLD16(gs0 + k0*BK, &sA[0][i0*1024]);   // DMA chunk k0 -> buf0
  GLD16(gs1 + k0*BK, &sA[0][i1*1024]);
  __syncthreads();

  const int swz = (c & 7) << 4;
  const int rb0 = c*ROWB + ((     g*16) ^ swz);
  const int rb1 = c*ROWB + ((64 + g*16) ^ swz);

  // 8-iter fused pipeline: DMA(kc+1) | x-load(kc+2) | compute(kc) | store(kc+2)
  for (int kc = 0; kc < KHALF; ++kc){
    const char* bufc = sA[kc & 1];
    if (kc+1 < KHALF){
      char* bufn = sA[(kc+1)&1];
      GLD16(gs0 + (k0+kc+1)*BK, &bufn[i0*1024]);
      GLD16(gs1 + (k0+kc+1)*BK, &bufn[i1*1024]);
    }
    float4 fa0, fa1, fb0, fb1;
    const bool cv = (kc+2 < KHALF);
    if (cv){
      const size_t oa = (size_t)r_a*HW_DIM + (k0+kc+2)*BK + c8_a*8;
      fa0 = *(const float4*)(xb + oa); fa1 = *(const float4*)(xb + oa + 4);
      if (vb){
        const size_t ob = (size_t)r_b*HW_DIM + (k0+kc+2)*BK + c8_b*8;
        fb0 = *(const float4*)(xb + ob); fb1 = *(const float4*)(xb + ob + 4);
      }
    }
    #pragma unroll
    for (int s = 0; s < 2; ++s){
      const char* p = bufc + (s ? rb1 : rb0);
      bf16x8 fw = *reinterpret_cast<const bf16x8*>(p + w*2048);
      #pragma unroll
      for (int j = 0; j < NT; ++j){
        bf16x8 fj = *reinterpret_cast<const bf16x8*>(p + j*2048);
        acc[j] = __builtin_amdgcn_mfma_f32_16x16x32_bf16(fw, fj, acc[j], 0, 0, 0);
      }
    }
    if (cv){
      const size_t oa = (size_t)r_a*HW_DIM + (k0+kc+2)*BK + c8_a*8;
      *reinterpret_cast<bf16x8*>(wb + oa) = pack8(fa0,fa1);
      if (vb){
        const size_t ob = (size_t)r_b*HW_DIM + (k0+kc+2)*BK + c8_b*8;
        *reinterpret_cast<bf16x8*>(wb + ob) = pack8(fb0,fb1);
      }
    }
    __syncthreads();
  }

  // store partial G (C/D layout: col=c, row-in-tile=g*4+i)
  float* pb = part + (size_t)(2*b + h) * GSIZE;
  #pragma unroll
  for (int j=0;j<NT;++j){
    #pragma unroll
    for (int i=0;i<4;++i){
      const int row = w*16 + g*4 + i;
      pb[row*PADC + j*16 + c] = acc[j][i];
    }
  }
}

// ================= kernel 2: combine + dcov + centering =================
__global__ __launch_bounds__(832, 4)
void dcov_finish_kernel(const float* __restrict__ part,
                        const float* __restrict__ temp,
                        float* __restrict__ out)
{
  __shared__ float d_lds[PADC];
  __shared__ float rs_lds[PADC];

  const int tid = threadIdx.x;
  const int b   = blockIdx.x;
  const int w   = tid >> 6;
  const int l   = tid & 63;
  const int g   = l >> 4;
  const int c   = l & 15;

  const float* p0 = part + (size_t)(2*b    ) * GSIZE;
  const float* p1 = part + (size_t)(2*b + 1) * GSIZE;
  const float et  = expf(temp[0]);

  // reload G = p0 + p1 into the same acc layout as kernel1
  f32x4 acc[NT];
  #pragma unroll
  for (int j=0;j<NT;++j){
    #pragma unroll
    for (int i=0;i<4;++i){
      const int idx = (w*16 + g*4 + i)*PADC + j*16 + c;
      acc[j][i] = p0[idx] + p1[idx];
    }
  }

  // diagonal -> d_lds (dcov_ii exactly 0 by construction)
  #pragma unroll
  for (int j=0;j<NT;++j){
    if (j == w){
      #pragma unroll
      for (int i=0;i<4;++i)
        if (c == g*4 + i) d_lds[j*16 + c] = acc[j][i];
    }
  }
  __syncthreads();

  float dr[4];
  #pragma unroll
  for (int i=0;i<4;++i) dr[i] = d_lds[w*16 + g*4 + i];
  float rsum[4] = {0.f,0.f,0.f,0.f};
  #pragma unroll
  for (int j=0;j<NT;++j){
    const float dc = d_lds[j*16 + c];
    const bool cvv = (j*16 + c) < C_DIM;
    #pragma unroll
    for (int i=0;i<4;++i){
      float v = dr[i] + dc - 2.0f*acc[j][i];
      v = fmaxf(v, 0.0f);
      v = sqrtf(fmaf(et, v, 1e-5f));
      acc[j][i] = v;
      if (cvv) rsum[i] += v;
    }
  }
  #pragma unroll
  for (int m=1;m<16;m<<=1){
    #pragma unroll
    for (int i=0;i<4;++i) rsum[i] += __shfl_xor(rsum[i], m, 64);
  }
  if (c == 0){
    #pragma unroll
    for (int i=0;i<4;++i) rs_lds[w*16 + g*4 + i] = rsum[i];
  }
  __syncthreads();

  float tot = 0.f;
  for (int r=0;r<C_DIM;++r) tot += rs_lds[r];
  const float inv  = 1.0f/(float)C_DIM;
  const float totm = tot*inv*inv;

  float* ob = out + b*(C_DIM*C_DIM);
  float rmr[4];
  #pragma unroll
  for (int i=0;i<4;++i) rmr[i] = rs_lds[w*16 + g*4 + i]*inv;
  #pragma unroll
  for (int j=0;j<NT;++j){
    const int col = j*16 + c;
    if (col < C_DIM){
      const float rmc = rs_lds[col]*inv;
      #pragma unroll
      for (int i=0;i<4;++i){
        const int row = w*16 + g*4 + i;
        if (row < C_DIM)
          ob[row*C_DIM + col] = rmr[i] + rmc - totm - acc[j][i];
      }
    }
  }
}

extern "C" void kernel_launch(void* const* d_in, const int* in_sizes, int n_in,
                              void* d_out, int out_size, void* d_ws, size_t ws_size,
                              hipStream_t stream) {
  const float* x    = (const float*)d_in[0];
  const float* temp = (const float*)d_in[1];
  float* out        = (float*)d_out;
  __hip_bfloat16* ws = (__hip_bfloat16*)d_ws;
  float* part       = (float*)((char*)d_ws + PART_OFF);
  gram_partial_kernel<<<dim3(512), dim3(832), 0, stream>>>(x, ws, part);
  dcov_finish_kernel <<<dim3(256), dim3(832), 0, stream>>>(part, temp, out);
}